// Round 5
// baseline (277.150 us; speedup 1.0000x reference)
//
#include <hip/hip_runtime.h>
#include <stdint.h>

#define NN 20000
#define NE 200000
#define NG 128
#define NJOBS 3125
#define SLOTS 1536   // (768/2 blocks per half) * 4 waves

typedef __attribute__((ext_vector_type(8))) short short8;
typedef __attribute__((ext_vector_type(4))) float f32x4;
typedef __attribute__((ext_vector_type(2))) unsigned int uint2v;

static __device__ __forceinline__ float bf2f(short s) {
    union { unsigned int u; float f; } x;
    x.u = ((unsigned int)(unsigned short)s) << 16;
    return x.f;
}
static __device__ __forceinline__ unsigned short f2bf(float f) {
    unsigned int u = __builtin_bit_cast(unsigned int, f);
    u += 0x7fffu + ((u >> 16) & 1u);
    return (unsigned short)(u >> 16);
}
// pack two floats into dword of two bf16 (a low, b high)
static __device__ __forceinline__ unsigned int pack2bf(float a, float b) {
    unsigned int u0 = __builtin_bit_cast(unsigned int, a) + 0x8000u;
    unsigned int u1 = __builtin_bit_cast(unsigned int, b) + 0x8000u;
    return __builtin_amdgcn_perm(u1, u0, 0x07060302u);
}
// per-wave dtype detect (bf16 low-short exponent-field statistics)
static __device__ __forceinline__ int detect_isbf(const unsigned int* x) {
    unsigned int u = x[threadIdx.x & 63];
    unsigned int el = (u >> 7) & 0xffu;
    unsigned long long bm = __ballot((el >= 100u) && (el <= 140u));
    return __popcll(bm) > 32;
}

// ------------------------------------------------------------------ prep:
// blocks [0,264): W2T[o][k'] (bf16 [32][1056]); block 1 extra: w1t/b1f;
// blocks [264,344): zero cnt[20000].
__global__ __launch_bounds__(256) void k_prep(
    const void* w2a, const void* b2a, const void* w2b, const void* b2b,
    const void* w1a, const void* b1a, const void* w1b, const void* b1b,
    const unsigned int* xdet,
    short* __restrict__ W2Ta, short* __restrict__ W2Tb,
    short* __restrict__ w1t_ws, float* __restrict__ b1f_ws,
    int* __restrict__ cnt) {
    const int isbf = detect_isbf(xdet);
    if (blockIdx.x == 1) {
        for (int i = threadIdx.x; i < 1024; i += 256) {
            int layer = i >> 9, jj = i & 511, c = jj >> 4, q = jj & 15;
            const void* w1p = layer ? w1b : w1a;
            w1t_ws[i] = isbf ? ((const short*)w1p)[q * 32 + c]
                             : (short)f2bf(((const float*)w1p)[q * 32 + c]);
        }
        for (int i = threadIdx.x; i < 64; i += 256) {
            int layer = i >> 5, c = i & 31;
            const void* b1p = layer ? b1b : b1a;
            b1f_ws[i] = isbf ? bf2f(((const short*)b1p)[c])
                             : ((const float*)b1p)[c];
        }
    }
    int t = blockIdx.x * 256 + threadIdx.x;
    if (t < 2 * 32 * 1056) {
        int layer = t / (32 * 1056);
        int r = t - layer * (32 * 1056);
        int o = r / 1056, kp = r - o * 1056;
        const void* w2 = layer ? w2b : w2a;
        const void* b2 = layer ? b2b : b2a;
        int idx; const void* sp;
        if (kp < 1024) { int kk = kp >> 5, i = kp & 31; idx = kk * 1024 + i * 32 + o; sp = w2; }
        else           { int i = kp - 1024;             idx = i * 32 + o;             sp = b2; }
        short v = isbf ? ((const short*)sp)[idx] : (short)f2bf(((const float*)sp)[idx]);
        (layer ? W2Tb : W2Ta)[o * 1056 + kp] = v;
        return;
    }
    int z = t - 2 * 32 * 1056;
    if (z < NN) cnt[z] = 0;
}

// ------------------------------------------------------------------ embed + hist:
// blocks [0,2500): h0 = lrelu(x@nfc_w + nfc_b); blocks [2500,2891): dst histogram
__global__ __launch_bounds__(256) void k_embed_hist(
    const void* x, const void* w, const void* b, const int* __restrict__ dst,
    float* __restrict__ h0, int* __restrict__ cnt) {
    if (blockIdx.x >= 2500) {
        int e = (blockIdx.x - 2500) * 512 + threadIdx.x;
        if (e < NE) atomicAdd(&cnt[dst[e]], 1);
        e += 256;
        if (e < NE) atomicAdd(&cnt[dst[e]], 1);
        return;
    }
    const int isbf = detect_isbf((const unsigned int*)x);
    __shared__ float wf[64 * 32];
    __shared__ float bfs[32];
    for (int i = threadIdx.x; i < 64 * 32; i += 256)
        wf[i] = isbf ? bf2f(((const short*)w)[i]) : ((const float*)w)[i];
    if (threadIdx.x < 32)
        bfs[threadIdx.x] = isbf ? bf2f(((const short*)b)[threadIdx.x])
                                : ((const float*)b)[threadIdx.x];
    __syncthreads();
    int t = blockIdx.x * 256 + threadIdx.x;
    int v = t >> 5, c = t & 31;
    float acc = bfs[c];
    if (isbf) {
        const short* xr = (const short*)x + v * 64;
#pragma unroll
        for (int q = 0; q < 64; ++q) acc += bf2f(xr[q]) * wf[q * 32 + c];
    } else {
        const float* xr = (const float*)x + v * 64;
#pragma unroll
        for (int q = 0; q < 64; ++q) acc += xr[q] * wf[q * 32 + c];
    }
    h0[t] = acc > 0.f ? acc : 0.01f * acc;
}

// ------------------------------------------------------------------ scan (1 block):
// exclusive prefix over cnt[20000] -> row_ptr[20001] + ptr_work copy; zero pooled
__global__ __launch_bounds__(1024) void k_scan(
    const int* __restrict__ cnt, int* __restrict__ row_ptr,
    int* __restrict__ ptr_work, float* __restrict__ pooled) {
    __shared__ int part[1024];
    const int t = threadIdx.x;
    for (int i = t; i < NG * 32; i += 1024) pooled[i] = 0.f;
    int loc[20];
    int s = 0;
    const int base = t * 20;
#pragma unroll
    for (int i = 0; i < 20; ++i) {
        loc[i] = s;
        int idx = base + i;
        s += (idx < NN) ? cnt[idx] : 0;
    }
    part[t] = s;
    __syncthreads();
    // inclusive scan over part
    for (int off = 1; off < 1024; off <<= 1) {
        int v = (t >= off) ? part[t - off] : 0;
        __syncthreads();
        part[t] += v;
        __syncthreads();
    }
    int excl = part[t] - s;
#pragma unroll
    for (int i = 0; i < 20; ++i) {
        int idx = base + i;
        if (idx <= NN) {
            int v = excl + loc[i];
            row_ptr[idx] = v;
            if (idx < NN) ptr_work[idx] = v;
        }
    }
}

// ------------------------------------------------------------------ scatter:
// sorted position p = ptr_work[dst[e]]++; src_s[p]=src[e]; ea_s[p]= bf16 row
__global__ __launch_bounds__(256) void k_scatter(
    const int* __restrict__ src, const int* __restrict__ dst,
    const void* ea, int* __restrict__ ptr_work,
    int* __restrict__ src_s, short* __restrict__ ea_s) {
    const int isbf = detect_isbf((const unsigned int*)ea);
    int e = blockIdx.x * 256 + threadIdx.x;
    if (e >= NE) return;
    int d = dst[e];
    int p = atomicAdd(&ptr_work[d], 1);
    src_s[p] = src[e];
    short8 row;
    if (isbf) {
        row = *(const short8*)((const short*)ea + (size_t)e * 16);
    } else {
        const float* q = (const float*)ea + (size_t)e * 16;
        f32x4 f0 = *(const f32x4*)q;
        f32x4 f1 = *(const f32x4*)(q + 4);
        f32x4 f2 = *(const f32x4*)(q + 8);
        f32x4 f3 = *(const f32x4*)(q + 12);
        union { unsigned int d[4]; short8 v; } a, bpk;
        a.d[0] = pack2bf(f0[0], f0[1]); a.d[1] = pack2bf(f0[2], f0[3]);
        a.d[2] = pack2bf(f1[0], f1[1]); a.d[3] = pack2bf(f1[2], f1[3]);
        bpk.d[0] = pack2bf(f2[0], f2[1]); bpk.d[1] = pack2bf(f2[2], f2[3]);
        bpk.d[2] = pack2bf(f3[0], f3[1]); bpk.d[3] = pack2bf(f3[2], f3[3]);
        union { short8 lo, hi; } ;
        *(short8*)&ea_s[(size_t)p * 16] = a.v;
        *(short8*)&ea_s[(size_t)p * 16 + 8] = bpk.v;
        return;
    }
    *(short8*)&ea_s[(size_t)p * 16] = row;
    // second half of row for bf16 path
    short8 row2 = *(const short8*)((const short*)ea + (size_t)e * 16 + 8);
    *(short8*)&ea_s[(size_t)p * 16 + 8] = row2;
}

// ------------------------------------------------------------------ edge kernel:
// msg = P @ W2' over sorted edges; K split in halves across blocks; writes
// bf16-packed partial messages (no atomics).  LDS 45.6KB -> 3 blocks/CU.
__global__ __launch_bounds__(256, 3) void k_edge(
    const float* __restrict__ h_in,   // [N,32] fp32
    const short* __restrict__ W2T,    // [32][1056] bf16
    const short* __restrict__ w1pre,  // [32][16] bf16 transposed (this layer)
    const float* __restrict__ b1pre,  // [32] fp32 (this layer)
    const int* __restrict__ src_s,    // [E] sorted
    const short* __restrict__ ea_s,   // [E][16] bf16 sorted
    unsigned int* __restrict__ msgA, unsigned int* __restrict__ msgB) {
    __shared__ __align__(16) short w2t[32 * 552];
    __shared__ __align__(16) short h1t[4 * 64 * 20];   // per-wave [64][20] bf16

    const int half = blockIdx.x & 1;
    const int k0   = half ? 512 : 0;
    const int S17  = half;               // 1 -> 17 K-steps, else 16
    const int KS   = half ? 552 : 520;   // LDS row stride (shorts)
    const int KLEN = half ? 544 : 512;
    unsigned int* __restrict__ msg_out = half ? msgB : msgA;

    { // stage W2T[o][k0..k0+KLEN) -> LDS
        int cpr = KLEN >> 3;
        int chunks = 32 * cpr;
        for (int idx = threadIdx.x; idx < chunks; idx += 256) {
            int o = idx / cpr, t8 = idx - o * cpr;
            *(short8*)&w2t[o * KS + (t8 << 3)] =
                *(const short8*)&W2T[o * 1056 + k0 + (t8 << 3)];
        }
    }
    __syncthreads();

    const int lane = threadIdx.x & 63;
    const int wid  = threadIdx.x >> 6;
    const int m    = lane & 15;
    const int quad = lane >> 4;
    const int wb   = wid * (64 * 20);

    // B-fragment of w1 (K padded 16->32 with zero rows -> quads 2,3 zero)
    short8 w1frag = {0, 0, 0, 0, 0, 0, 0, 0};
    if (quad < 2) {
        int c = m + (half << 4);
        w1frag = *(const short8*)&w1pre[c * 16 + ((quad & 1) << 3)];
    }
    const float b1v = b1pre[m + (half << 4)];
    const f32x4 zero4 = {0.f, 0.f, 0.f, 0.f};

    int j = (blockIdx.x >> 1) * 4 + wid;  // slot in [0,1536)

    // ---- prologue: land job j inputs + src for j+SLOTS ----
    short8 eafc[4];
    f32x4 hs[4][2];
    int srcn[4];
    {
        const int e0 = j << 6;
        int s0[4];
#pragma unroll
        for (int mt = 0; mt < 4; ++mt) {
            eafc[mt] = *(const short8*)&ea_s[(size_t)(e0 + mt * 16 + m) * 16 + ((quad & 1) << 3)];
            s0[mt] = src_s[e0 + mt * 16 + m];
        }
#pragma unroll
        for (int mt = 0; mt < 4; ++mt) {
            const float* hr = h_in + (size_t)s0[mt] * 32 + (quad << 3);
            hs[mt][0] = *(const f32x4*)hr;
            hs[mt][1] = *(const f32x4*)(hr + 4);
        }
        const int en = (j + SLOTS) << 6;
#pragma unroll
        for (int mt = 0; mt < 4; ++mt) srcn[mt] = src_s[en + mt * 16 + m];
    }

    while (j < NJOBS) {
        const int e0 = j << 6;
        const int jn = j + SLOTS;

        // ---- phase 1: h1 = relu(ea@w1+b1) -> transposed bf16 in LDS ----
#pragma unroll
        for (int mt = 0; mt < 4; ++mt) {
            f32x4 hacc = __builtin_amdgcn_mfma_f32_16x16x32_bf16(
                eafc[mt], w1frag, zero4, 0, 0, 0);
#pragma unroll
            for (int r = 0; r < 4; ++r) {
                float v = hacc[r] + b1v;
                v = v > 0.f ? v : 0.f;
                h1t[wb + (mt * 16 + quad * 4 + r) * 20 + m] = (short)f2bf(v);
            }
        }
        if (half) h1t[wb + lane * 20 + 16] = (short)0x3F80;  // bias row scale 1.0
        __asm volatile("s_waitcnt lgkmcnt(0)" ::: "memory");

        // prefetch next job's ea
        if (jn < NJOBS) {
            const int en = jn << 6;
#pragma unroll
            for (int mt = 0; mt < 4; ++mt)
                eafc[mt] = *(const short8*)&ea_s[(size_t)(en + mt * 16 + m) * 16 + ((quad & 1) << 3)];
        }

        // ---- phase 2: K loop ----
        f32x4 acc0[4], acc1[4];
#pragma unroll
        for (int mt = 0; mt < 4; ++mt) { acc0[mt] = zero4; acc1[mt] = zero4; }

#pragma unroll
        for (int c = 0; c < 4; ++c) {
            uint2v h4[4];
#pragma unroll
            for (int mt = 0; mt < 4; ++mt)
                h4[mt] = *(const uint2v*)&h1t[wb + (mt * 16 + m) * 20 + (c << 2)];
#pragma unroll
            for (int u = 0; u < 4; ++u) {
                const int s = (c << 2) + u;
                short8 bf0 = *(const short8*)&w2t[m * KS + (s << 5) + (quad << 3)];
                short8 bf1 = *(const short8*)&w2t[(m + 16) * KS + (s << 5) + (quad << 3)];
#pragma unroll
                for (int mt = 0; mt < 4; ++mt) {
                    unsigned int d = (u < 2) ? h4[mt][0] : h4[mt][1];
                    unsigned int sb = (u & 1) ? (d & 0xffff0000u) : (d << 16);
                    float sc = __builtin_bit_cast(float, sb);
                    union { unsigned int du[4]; short8 v; } a;
#pragma unroll
                    for (int p = 0; p < 4; ++p) {
                        f32x4 hv = hs[mt][p >> 1];
                        a.du[p] = pack2bf(sc * hv[(p & 1) * 2], sc * hv[(p & 1) * 2 + 1]);
                    }
                    acc0[mt] = __builtin_amdgcn_mfma_f32_16x16x32_bf16(a.v, bf0, acc0[mt], 0, 0, 0);
                    acc1[mt] = __builtin_amdgcn_mfma_f32_16x16x32_bf16(a.v, bf1, acc1[mt], 0, 0, 0);
                }
            }
        }
        if (S17) {  // tail step s=16 (bias row)
            const int s = 16;
            short8 bf0 = *(const short8*)&w2t[m * KS + (s << 5) + (quad << 3)];
            short8 bf1 = *(const short8*)&w2t[(m + 16) * KS + (s << 5) + (quad << 3)];
#pragma unroll
            for (int mt = 0; mt < 4; ++mt) {
                unsigned int d = *(const unsigned int*)&h1t[wb + (mt * 16 + m) * 20 + 16];
                float sc = __builtin_bit_cast(float, d << 16);
                union { unsigned int du[4]; short8 v; } a;
#pragma unroll
                for (int p = 0; p < 4; ++p) {
                    f32x4 hv = hs[mt][p >> 1];
                    a.du[p] = pack2bf(sc * hv[(p & 1) * 2], sc * hv[(p & 1) * 2 + 1]);
                }
                acc0[mt] = __builtin_amdgcn_mfma_f32_16x16x32_bf16(a.v, bf0, acc0[mt], 0, 0, 0);
                acc1[mt] = __builtin_amdgcn_mfma_f32_16x16x32_bf16(a.v, bf1, acc1[mt], 0, 0, 0);
            }
        }

        // prefetch next job's hsrc + src for j+2*SLOTS
        if (jn < NJOBS) {
#pragma unroll
            for (int mt = 0; mt < 4; ++mt) {
                const float* hr = h_in + (size_t)srcn[mt] * 32 + (quad << 3);
                hs[mt][0] = *(const f32x4*)hr;
                hs[mt][1] = *(const f32x4*)(hr + 4);
            }
            const int jn2 = jn + SLOTS;
            if (jn2 < NJOBS) {
                const int en2 = jn2 << 6;
#pragma unroll
                for (int mt = 0; mt < 4; ++mt) srcn[mt] = src_s[en2 + mt * 16 + m];
            }
        }

        // ---- epilogue: plain packed-bf16 stores (cols m and m+16 per dword) ----
#pragma unroll
        for (int mt = 0; mt < 4; ++mt) {
#pragma unroll
            for (int r = 0; r < 4; ++r) {
                msg_out[(size_t)(e0 + mt * 16 + quad * 4 + r) * 16 + m] =
                    pack2bf(acc0[mt][r], acc1[mt][r]);
            }
        }
        j = jn;
    }
}

// ------------------------------------------------------------------ aggregate:
// acc = h_prev@root + bias + sum(msgA+msgB rows) per dst; lrelu.
// mode 0: write h1b.  mode 1: write atom_embs (dtype per flag) + pooled atomics.
__global__ __launch_bounds__(256) void k_agg(
    const unsigned int* __restrict__ msgA, const unsigned int* __restrict__ msgB,
    const int* __restrict__ row_ptr, const float* __restrict__ h_prev,
    const void* root, const void* bias, const unsigned int* xdet,
    const int* __restrict__ batch, int mode,
    float* __restrict__ h1b, void* __restrict__ out, float* pooled) {
    const int isbf = detect_isbf(xdet);
    __shared__ float rf[32 * 32];
    __shared__ float bfs[32];
    for (int i = threadIdx.x; i < 1024; i += 256)
        rf[i] = isbf ? bf2f(((const short*)root)[i]) : ((const float*)root)[i];
    if (threadIdx.x < 32)
        bfs[threadIdx.x] = isbf ? bf2f(((const short*)bias)[threadIdx.x])
                                : ((const float*)bias)[threadIdx.x];
    __syncthreads();
    int t = blockIdx.x * 256 + threadIdx.x;
    if (t >= NN * 32) return;
    int d = t >> 5, c = t & 31;
    const float* hr = h_prev + (size_t)d * 32;
    float acc = bfs[c];
#pragma unroll
    for (int q = 0; q < 32; ++q) acc += hr[q] * rf[q * 32 + c];
    const int b0 = row_ptr[d], b1 = row_ptr[d + 1];
    const int ci = c & 15;
    const int hi = c >> 4;
    float s = 0.f;
    for (int e = b0; e < b1; ++e) {
        unsigned int da = msgA[(size_t)e * 16 + ci];
        unsigned int db = msgB[(size_t)e * 16 + ci];
        unsigned int ba = hi ? (da & 0xffff0000u) : (da << 16);
        unsigned int bb = hi ? (db & 0xffff0000u) : (db << 16);
        s += __builtin_bit_cast(float, ba) + __builtin_bit_cast(float, bb);
    }
    float v = acc + s;
    v = v > 0.f ? v : 0.01f * v;
    if (mode == 0) {
        h1b[t] = v;
    } else {
        if (isbf) ((short*)out)[4096 + t] = (short)f2bf(v);
        else      ((float*)out)[4096 + t] = v;
        atomicAdd(&pooled[batch[d] * 32 + c], v);
    }
}

// ------------------------------------------------------------------ graph head
__global__ __launch_bounds__(64) void k_graph_out(
    const float* __restrict__ pooled, const void* fcw, const void* fcb,
    const unsigned int* xdet, void* __restrict__ out) {
    const int isbf = detect_isbf(xdet);
    int g = blockIdx.x;
    int t = threadIdx.x;
    __shared__ float pn[32];
    if (t < 32) {
        float p = pooled[g * 32 + t];
        float sq = p * p;
#pragma unroll
        for (int o = 16; o > 0; o >>= 1) sq += __shfl_xor(sq, o, 64);
        float inv = 1.0f / fmaxf(sqrtf(sq), 1e-12f);
        pn[t] = p * inv;
    }
    __syncthreads();
    if (t < 32) {
        float acc = isbf ? bf2f(((const short*)fcb)[t]) : ((const float*)fcb)[t];
#pragma unroll
        for (int q = 0; q < 32; ++q) {
            float wv = isbf ? bf2f(((const short*)fcw)[q * 32 + t])
                            : ((const float*)fcw)[q * 32 + t];
            acc += pn[q] * wv;
        }
        if (isbf) ((short*)out)[g * 32 + t] = (short)f2bf(acc);
        else      ((float*)out)[g * 32 + t] = acc;
    }
}

extern "C" void kernel_launch(void* const* d_in, const int* in_sizes, int n_in,
                              void* d_out, int out_size, void* d_ws, size_t ws_size,
                              hipStream_t stream) {
    (void)in_sizes; (void)n_in; (void)out_size; (void)ws_size;
    const void* x     = d_in[0];
    const int*  eidx  = (const int*)d_in[1];
    const void* ea    = d_in[2];
    const int*  batch = (const int*)d_in[3];
    const void* nfcw  = d_in[5];
    const void* nfcb  = d_in[6];
    const void* e1w1  = d_in[7];
    const void* e1b1  = d_in[8];
    const void* e1w2  = d_in[9];
    const void* e1b2  = d_in[10];
    const void* root1 = d_in[11];
    const void* bias1 = d_in[12];
    const void* e2w1  = d_in[13];
    const void* e2b1  = d_in[14];
    const void* e2w2  = d_in[15];
    const void* e2b2  = d_in[16];
    const void* root2 = d_in[17];
    const void* bias2 = d_in[18];
    const void* fcw   = d_in[19];
    const void* fcb   = d_in[20];
    const unsigned int* xdet = (const unsigned int*)x;

    char* ws = (char*)d_ws;
    float* h0     = (float*)ws;        ws += (size_t)NN * 32 * 4;    // 2.56 MB
    float* h1b    = (float*)ws;        ws += (size_t)NN * 32 * 4;    // 2.56 MB
    unsigned int* msgA = (unsigned int*)ws; ws += (size_t)NE * 16 * 4; // 12.8 MB
    unsigned int* msgB = (unsigned int*)ws; ws += (size_t)NE * 16 * 4; // 12.8 MB
    short* ea_s   = (short*)ws;        ws += (size_t)NE * 16 * 2;    // 6.4 MB
    int*   src_s  = (int*)ws;          ws += (size_t)NE * 4;         // 0.8 MB
    short* W2T1   = (short*)ws;        ws += 32 * 1056 * 2;
    short* W2T2   = (short*)ws;        ws += 32 * 1056 * 2;
    short* w1t_ws = (short*)ws;        ws += 1024 * 2;
    float* b1f_ws = (float*)ws;        ws += 64 * 4;
    int*   cnt    = (int*)ws;          ws += (size_t)NN * 4;
    int*   row_ptr= (int*)ws;          ws += (size_t)(NN + 8) * 4;
    int*   ptr_wk = (int*)ws;          ws += (size_t)NN * 4;
    float* pooled = (float*)ws;        ws += NG * 32 * 4;

    const int* srcp = eidx;
    const int* dstp = eidx + NE;

    // 1: weights prep + cnt zero  (264 W2T blocks + 79 cnt blocks)
    k_prep<<<344, 256, 0, stream>>>(
        e1w2, e1b2, e2w2, e2b2, e1w1, e1b1, e2w1, e2b1, xdet,
        W2T1, W2T2, w1t_ws, b1f_ws, cnt);
    // 2: node embed + dst histogram
    k_embed_hist<<<2500 + 391, 256, 0, stream>>>(x, nfcw, nfcb, dstp, h0, cnt);
    // 3: prefix scan -> row_ptr, ptr_work; zero pooled
    k_scan<<<1, 1024, 0, stream>>>(cnt, row_ptr, ptr_wk, pooled);
    // 4: counting-sort scatter (src_s, ea_s in dst-sorted order)
    k_scatter<<<(NE + 255) / 256, 256, 0, stream>>>(srcp, dstp, ea, ptr_wk, src_s, ea_s);
    // 5-6: layer 1
    k_edge<<<768, 256, 0, stream>>>(h0, W2T1, w1t_ws, b1f_ws, src_s, ea_s, msgA, msgB);
    k_agg<<<2500, 256, 0, stream>>>(msgA, msgB, row_ptr, h0, root1, bias1, xdet,
                                    batch, 0, h1b, d_out, pooled);
    // 7-8: layer 2
    k_edge<<<768, 256, 0, stream>>>(h1b, W2T2, w1t_ws + 512, b1f_ws + 32, src_s, ea_s, msgA, msgB);
    k_agg<<<2500, 256, 0, stream>>>(msgA, msgB, row_ptr, h1b, root2, bias2, xdet,
                                    batch, 1, h1b, d_out, pooled);
    // 9: graph head
    k_graph_out<<<NG, 64, 0, stream>>>(pooled, fcw, fcb, xdet, d_out);
}